// Round 11
// baseline (167.955 us; speedup 1.0000x reference)
//
#include <hip/hip_runtime.h>

#define RES   64
#define RES2  4096
#define RES3  262144
#define CIN   16
#define COUT  32
#define NWH (27*CIN*COUT)             // 13824 weight halfs, [tap][hi][o][c8]

// conv tile: 2(z) x 4(y) x 64(x), 512 threads (8 waves), fused fp32->fp16
// staging. LDS x tile: rows R=(iz*6+iy)*2+hi, iz=0..3, iy=0..5 -> 48 rows
// x 68 chunks x 16 B. Chunk c holds gx=c-1; c=0,65 are zero (x pad), 66/67 pad.
#define ROWB  1088
#define XT_BYTES (48*ROWB)            // 52224 -> 3 resident blocks/CU
#define LDS_BYTES XT_BYTES

typedef _Float16 f16x8 __attribute__((ext_vector_type(8)));
typedef float   f32x16 __attribute__((ext_vector_type(16)));

static __device__ __forceinline__ unsigned int pack2(float v0, float v1) {
    _Float16 h0 = (_Float16)v0;
    _Float16 h1 = (_Float16)v1;
    unsigned short u0 = __builtin_bit_cast(unsigned short, h0);
    unsigned short u1 = __builtin_bit_cast(unsigned short, h1);
    return (unsigned int)u0 | ((unsigned int)u1 << 16);
}

// ---- Kernel 1: weights fp32 [o][ci][27] -> fp16 [tap][hi][o][c8] ---------
__global__ __launch_bounds__(256) void wtrans_kernel(
    const float* __restrict__ w, _Float16* __restrict__ wtg) {
    int i = blockIdx.x * 256 + threadIdx.x;
    if (i >= NWH) return;
    int tap = i >> 9;
    int hi  = (i >> 8) & 1;
    int o   = (i >> 3) & 31;
    int c   = i & 7;
    wtg[i] = (_Float16)w[(o * CIN + hi * 8 + c) * 27 + tap];
}

// ---- Kernel 2: fused stage(fp32->fp16) + MFMA conv + masked store --------
__global__ __launch_bounds__(512, 6) void conv_kernel(
    const float* __restrict__ x, const char* __restrict__ wtgb,
    float* __restrict__ out) {

    extern __shared__ char smem[];
    char* xt = smem;                  // [R:48][68][16B]

    // 1024 blocks, bijective XCD swizzle (1024 % 8 == 0)
    int bid = blockIdx.x;
    int sb  = (bid & 7) * 128 + (bid >> 3);
    int b   = sb >> 9;                // batch
    int zt  = (sb >> 4) & 31;        // z-tile (TZ=2)
    int yt  = sb & 15;                // y-tile (TY=4)
    int z0 = zt * 2, y0 = yt * 4;

    int tid  = threadIdx.x;
    int lane = tid & 63;
    int wv   = tid >> 6;              // 0..7
    int hi   = lane >> 5;
    int l31  = lane & 31;

    // ---- preload ALL 27 weight fragments into VGPRs (issues first; their
    //      latency hides under the staging phase; MFMA loop has no vmcnt) ----
    const char* wtab = wtgb + hi * 512 + l31 * 16;
    f16x8 wf[27];
    #pragma unroll
    for (int t = 0; t < 27; ++t) wf[t] = *(const f16x8*)(wtab + t * 1024);

    // ---- fused staging: 24 (iz,iy) pairs, 3 per wave ----
    const float* xb = x + (size_t)b * CIN * RES3;
    const uint4 zz = make_uint4(0u, 0u, 0u, 0u);
    #pragma unroll
    for (int j = 0; j < 3; ++j) {
        int p = wv * 3 + j;                        // 0..23
        int iz = p / 6, iy = p - iz * 6;
        int gz = z0 + iz - 1, gy = y0 + iy - 1;
        char* d0 = xt + (p * 2) * ROWB;            // hi=0 row; hi=1 at +ROWB
        uint4 lo = zz, hh = zz;
        if (((unsigned)gz < 64u) && ((unsigned)gy < 64u)) {   // uniform branch
            const float* sp = xb + gz * RES2 + gy * RES + lane;   // gx = lane
            float v0  = sp[0];          float v1  = sp[RES3];
            float v2  = sp[2 * RES3];   float v3  = sp[3 * RES3];
            float v4  = sp[4 * RES3];   float v5  = sp[5 * RES3];
            float v6  = sp[6 * RES3];   float v7  = sp[7 * RES3];
            float v8  = sp[8 * RES3];   float v9  = sp[9 * RES3];
            float v10 = sp[10 * RES3];  float v11 = sp[11 * RES3];
            float v12 = sp[12 * RES3];  float v13 = sp[13 * RES3];
            float v14 = sp[14 * RES3];  float v15 = sp[15 * RES3];
            lo = make_uint4(pack2(v0, v1),  pack2(v2, v3),
                            pack2(v4, v5),  pack2(v6, v7));
            hh = make_uint4(pack2(v8, v9),  pack2(v10, v11),
                            pack2(v12, v13), pack2(v14, v15));
        }
        *(uint4*)(d0 + (lane + 1) * 16)        = lo;   // chunk c = gx+1
        *(uint4*)(d0 + ROWB + (lane + 1) * 16) = hh;
        if (lane < 4) {                         // boundary chunks 0,65,66,67
            int cz = (lane == 0) ? 0 : (64 + lane);
            *(uint4*)(d0 + cz * 16)        = zz;
            *(uint4*)(d0 + ROWB + cz * 16) = zz;
        }
    }
    __syncthreads();

    // ---- wave -> (oz, oy): one z row, both x-halves ----
    int oy = wv & 3;
    int oz = wv >> 2;                 // 0..1

    const char* xbase = xt + hi * ROWB + l31 * 16;

    f32x16 acc0 = {};   // xh0
    f32x16 acc1 = {};   // xh1

    __builtin_amdgcn_s_setprio(1);
    #pragma unroll
    for (int g = 0; g < 3; ++g) {                 // dz = g-1; slab iz = oz+g
        #pragma unroll
        for (int dyp = 0; dyp < 3; ++dyp) {       // dy = dyp-1
            const char* xrow = xbase + (((oz + g) * 6 + (oy + dyp)) * 2) * ROWB;
            #pragma unroll
            for (int dxp = 0; dxp < 3; ++dxp) {
                f16x8 b0 = *(const f16x8*)(xrow + dxp * 16);
                f16x8 b1 = *(const f16x8*)(xrow + 512 + dxp * 16);
                acc0 = __builtin_amdgcn_mfma_f32_32x32x16_f16(
                    wf[g * 9 + dyp * 3 + dxp], b0, acc0, 0, 0, 0);
                acc1 = __builtin_amdgcn_mfma_f32_32x32x16_f16(
                    wf[g * 9 + dyp * 3 + dxp], b1, acc1, 0, 0, 0);
            }
        }
    }
    __builtin_amdgcn_s_setprio(0);

    // ---- epilogue: occupancy masks (&0x7FFF kills -0.0), full-line stores --
    int R = ((oz + 1) * 6 + (oy + 1)) * 2;        // hi=0 row of center voxel
    unsigned m0, m1;
    {
        const char* mp = xt + R * ROWB + (l31 + 1) * 16;          // xh0
        uint4 a = *(const uint4*)(mp);
        uint4 c = *(const uint4*)(mp + ROWB);
        m0 = (a.x | a.y | a.z | a.w | c.x | c.y | c.z | c.w) & 0x7FFF7FFFu;
        const char* mq = xt + R * ROWB + (32 + l31 + 1) * 16;     // xh1
        uint4 d = *(const uint4*)(mq);
        uint4 e = *(const uint4*)(mq + ROWB);
        m1 = (d.x | d.y | d.z | d.w | e.x | e.y | e.z | e.w) & 0x7FFF7FFFu;
    }
    bool o0 = m0 != 0u, o1 = m1 != 0u;

    size_t vaddr = (size_t)(z0 + oz) * RES2 + (y0 + oy) * RES + l31;

    #pragma unroll
    for (int r = 0; r < 16; ++r) {
        int o = (r & 3) + 8 * (r >> 2) + 4 * hi;
        float* pl = out + ((size_t)(b * COUT + o) << 18);
        pl[vaddr]      = o0 ? acc0[r] : 0.0f;   // both halves from one wave
        pl[vaddr + 32] = o1 ? acc1[r] : 0.0f;   // -> full 256B line
    }
}

extern "C" void kernel_launch(void* const* d_in, const int* in_sizes, int n_in,
                              void* d_out, int out_size, void* d_ws, size_t ws_size,
                              hipStream_t stream) {
    const float* x = (const float*)d_in[0];   // [2,16,64,64,64]
    const float* w = (const float*)d_in[1];   // [1,32,16,3,3,3]
    float* out = (float*)d_out;               // [2,32,64,64,64]

    _Float16* wtg = (_Float16*)d_ws;          // 27648 B

    (void)hipFuncSetAttribute(reinterpret_cast<const void*>(conv_kernel),
                              hipFuncAttributeMaxDynamicSharedMemorySize, LDS_BYTES);

    wtrans_kernel<<<(NWH + 255) / 256, 256, 0, stream>>>(w, wtg);
    conv_kernel<<<1024, 512, LDS_BYTES, stream>>>(x, (const char*)wtg, out);
}

// Round 12
// 111.250 us; speedup vs baseline: 1.5097x; 1.5097x over previous
//
#include <hip/hip_runtime.h>

#define RES   64
#define RES2  4096
#define RES3  262144
#define CIN   16
#define COUT  32
#define NWH (27*CIN*COUT)             // 13824 weight halfs, [tap][hi][o][c8]

// conv tile: 2(z) x 2(y) x 64(x), 256 threads (4 waves), fused fp32->fp16
// staging. LDS x tile: rows R=(iz*4+iy)*2+hi, iz=0..3, iy=0..3 -> 32 rows
// x 68 chunks x 16 B. Chunk c holds gx=c-1; c=0,65 zero (x pad), 66/67 pad.
// 34816 B LDS -> 4 resident blocks/CU (4 independent barrier groups).
#define ROWB  1088
#define XT_BYTES (32*ROWB)            // 34816
#define LDS_BYTES XT_BYTES

typedef _Float16 f16x8 __attribute__((ext_vector_type(8)));
typedef float   f32x16 __attribute__((ext_vector_type(16)));

static __device__ __forceinline__ unsigned int pack2(float v0, float v1) {
    _Float16 h0 = (_Float16)v0;
    _Float16 h1 = (_Float16)v1;
    unsigned short u0 = __builtin_bit_cast(unsigned short, h0);
    unsigned short u1 = __builtin_bit_cast(unsigned short, h1);
    return (unsigned int)u0 | ((unsigned int)u1 << 16);
}

// ---- Kernel 1: weights fp32 [o][ci][27] -> fp16 [tap][hi][o][c8] ---------
__global__ __launch_bounds__(256) void wtrans_kernel(
    const float* __restrict__ w, _Float16* __restrict__ wtg) {
    int i = blockIdx.x * 256 + threadIdx.x;
    if (i >= NWH) return;
    int tap = i >> 9;
    int hi  = (i >> 8) & 1;
    int o   = (i >> 3) & 31;
    int c   = i & 7;
    wtg[i] = (_Float16)w[(o * CIN + hi * 8 + c) * 27 + tap];
}

// ---- Kernel 2: fused stage(fp32->fp16) + MFMA conv + masked store --------
__global__ __launch_bounds__(256, 4) void conv_kernel(
    const float* __restrict__ x, const char* __restrict__ wtgb,
    float* __restrict__ out) {

    extern __shared__ char smem[];
    char* xt = smem;                  // [R:32][68][16B]

    // 2048 blocks, bijective XCD swizzle (2048 % 8 == 0)
    int bid = blockIdx.x;
    int sb  = (bid & 7) * 256 + (bid >> 3);
    int b   = sb >> 10;               // batch
    int zt  = (sb >> 5) & 31;         // z-tile (TZ=2)
    int yt  = sb & 31;                // y-tile (TY=2)
    int z0 = zt * 2, y0 = yt * 2;

    int tid  = threadIdx.x;
    int lane = tid & 63;
    int wv   = tid >> 6;              // 0..3
    int hi   = lane >> 5;
    int l31  = lane & 31;

    // ---- fused staging: 16 (iz,iy) pairs, 4 per wave ----
    const float* xb = x + (size_t)b * CIN * RES3;
    const uint4 zz = make_uint4(0u, 0u, 0u, 0u);
    #pragma unroll
    for (int j = 0; j < 4; ++j) {
        int p = wv * 4 + j;                        // 0..15
        int iz = p >> 2, iy = p & 3;
        int gz = z0 + iz - 1, gy = y0 + iy - 1;
        char* d0 = xt + (p * 2) * ROWB;            // hi=0 row; hi=1 at +ROWB
        uint4 lo = zz, hh = zz;
        if (((unsigned)gz < 64u) && ((unsigned)gy < 64u)) {   // uniform branch
            const float* sp = xb + gz * RES2 + gy * RES + lane;   // gx = lane
            float v0  = sp[0];          float v1  = sp[RES3];
            float v2  = sp[2 * RES3];   float v3  = sp[3 * RES3];
            float v4  = sp[4 * RES3];   float v5  = sp[5 * RES3];
            float v6  = sp[6 * RES3];   float v7  = sp[7 * RES3];
            float v8  = sp[8 * RES3];   float v9  = sp[9 * RES3];
            float v10 = sp[10 * RES3];  float v11 = sp[11 * RES3];
            float v12 = sp[12 * RES3];  float v13 = sp[13 * RES3];
            float v14 = sp[14 * RES3];  float v15 = sp[15 * RES3];
            lo = make_uint4(pack2(v0, v1),  pack2(v2, v3),
                            pack2(v4, v5),  pack2(v6, v7));
            hh = make_uint4(pack2(v8, v9),  pack2(v10, v11),
                            pack2(v12, v13), pack2(v14, v15));
        }
        *(uint4*)(d0 + (lane + 1) * 16)        = lo;   // chunk c = gx+1
        *(uint4*)(d0 + ROWB + (lane + 1) * 16) = hh;
        if (lane < 4) {                         // boundary chunks 0,65,66,67
            int cz = (lane == 0) ? 0 : (64 + lane);
            *(uint4*)(d0 + cz * 16)        = zz;
            *(uint4*)(d0 + ROWB + cz * 16) = zz;
        }
    }
    __syncthreads();

    // ---- wave -> (oz, oy): one output voxel-row, both x-halves ----
    int oy = wv & 1;
    int oz = wv >> 1;                 // 0..1

    const char* xbase = xt + hi * ROWB + l31 * 16;
    const char* wtab  = wtgb + hi * 512 + l31 * 16;

    f32x16 acc0 = {};   // xh0
    f32x16 acc1 = {};   // xh1

    #pragma unroll
    for (int g = 0; g < 3; ++g) {                 // dz = g-1; slab iz = oz+g
        #pragma unroll
        for (int dyp = 0; dyp < 3; ++dyp) {       // dy = dyp-1
            const char* wp = wtab + (size_t)(g * 9 + dyp * 3) * 1024;
            f16x8 wf0 = *(const f16x8*)(wp);          // L1-hot global loads
            f16x8 wf1 = *(const f16x8*)(wp + 1024);
            f16x8 wf2 = *(const f16x8*)(wp + 2048);
            const char* xrow = xbase + (((oz + g) * 4 + (oy + dyp)) * 2) * ROWB;
            #pragma unroll
            for (int dxp = 0; dxp < 3; ++dxp) {
                f16x8 wf = (dxp == 0) ? wf0 : ((dxp == 1) ? wf1 : wf2);
                f16x8 b0 = *(const f16x8*)(xrow + dxp * 16);
                f16x8 b1 = *(const f16x8*)(xrow + 512 + dxp * 16);
                acc0 = __builtin_amdgcn_mfma_f32_32x32x16_f16(wf, b0, acc0, 0, 0, 0);
                acc1 = __builtin_amdgcn_mfma_f32_32x32x16_f16(wf, b1, acc1, 0, 0, 0);
            }
        }
    }

    // ---- epilogue: occupancy masks (&0x7FFF kills -0.0), full-line stores --
    int R = ((oz + 1) * 4 + (oy + 1)) * 2;        // hi=0 row of center voxel
    unsigned m0, m1;
    {
        const char* mp = xt + R * ROWB + (l31 + 1) * 16;          // xh0
        uint4 a = *(const uint4*)(mp);
        uint4 c = *(const uint4*)(mp + ROWB);
        m0 = (a.x | a.y | a.z | a.w | c.x | c.y | c.z | c.w) & 0x7FFF7FFFu;
        const char* mq = xt + R * ROWB + (32 + l31 + 1) * 16;     // xh1
        uint4 d = *(const uint4*)(mq);
        uint4 e = *(const uint4*)(mq + ROWB);
        m1 = (d.x | d.y | d.z | d.w | e.x | e.y | e.z | e.w) & 0x7FFF7FFFu;
    }
    bool o0 = m0 != 0u, o1 = m1 != 0u;

    size_t vaddr = (size_t)(z0 + oz) * RES2 + (y0 + oy) * RES + l31;

    #pragma unroll
    for (int r = 0; r < 16; ++r) {
        int o = (r & 3) + 8 * (r >> 2) + 4 * hi;
        float* pl = out + ((size_t)(b * COUT + o) << 18);
        pl[vaddr]      = o0 ? acc0[r] : 0.0f;   // both halves from one wave
        pl[vaddr + 32] = o1 ? acc1[r] : 0.0f;   // -> full 256B line
    }
}

extern "C" void kernel_launch(void* const* d_in, const int* in_sizes, int n_in,
                              void* d_out, int out_size, void* d_ws, size_t ws_size,
                              hipStream_t stream) {
    const float* x = (const float*)d_in[0];   // [2,16,64,64,64]
    const float* w = (const float*)d_in[1];   // [1,32,16,3,3,3]
    float* out = (float*)d_out;               // [2,32,64,64,64]

    _Float16* wtg = (_Float16*)d_ws;          // 27648 B

    (void)hipFuncSetAttribute(reinterpret_cast<const void*>(conv_kernel),
                              hipFuncAttributeMaxDynamicSharedMemorySize, LDS_BYTES);

    wtrans_kernel<<<(NWH + 255) / 256, 256, 0, stream>>>(w, wtg);
    conv_kernel<<<2048, 256, LDS_BYTES, stream>>>(x, (const char*)wtg, out);
}